// Round 5
// baseline (761.591 us; speedup 1.0000x reference)
//
#include <hip/hip_runtime.h>
#include <hip/hip_bf16.h>
#include <math.h>
#include <float.h>

#define BB    64
#define CCH   256
#define KKE   1024
#define HWN   1024
#define NTOT  (BB*HWN)          // 65536
#define OUT_ELE (BB*CCH*HWN)    // 16777216
#define LOSS_OFF 0
#define OUT_OFF  1
#define PERP_OFF (1 + OUT_ELE)
#define ENC_OFF  (2 + OUT_ELE)   // byte off % 16 == 8 -> float2 stores only

// workspace layout (bytes)
#define WS_IDX    0               // int[65536]
#define WS_ANORM  262144          // float[65536]
#define WS_HIST   524288          // uint[1024]
#define WS_BNORM  528384          // float[1024]
#define WS_MISC   532480          // [0]=lossacc (float), [1]=counter (int)
#define WS_LIST   536576          // int[65536]
#define WS_EMBT   798720          // float[256*1024]
#define WS_EHI    1847296         // bf16[8][1024][32] chunked
#define WS_ELO    2371584
#define WS_CD1    2895872         // float[8][65536]
#define WS_CK1    4993024         // int[8][65536]
#define WS_CD2    7090176         // float[8][65536]
// end ~9.2 MB

typedef __attribute__((ext_vector_type(4))) float f32x4;
typedef __attribute__((ext_vector_type(8))) short s16x8;

#define TAU 2e-4f
#define APAD 36   // row pitch in shorts: 72 B -> all-distinct even bank starts (2-way max = free)

// merge two (d1,k1,d2) candidate sets; first-index tie-break
__device__ inline void merge_cand(float& d1, int& k1, float& d2,
                                  float od1, int ok1, float od2) {
    bool w = (od1 < d1) || (od1 == d1 && ok1 < k1);
    float loser_d1 = w ? d1 : od1;
    float winner_d2 = w ? od2 : d2;
    d2 = fminf(winner_d2, loser_d1);
    if (w) { d1 = od1; k1 = ok1; }
}

// ---------------- Kernel 1: transpose emb, ||e||^2 fp64, bf16 split of emb, zero accums
__global__ __launch_bounds__(256) void prep_kernel(const float* __restrict__ emb,
                                                   float* __restrict__ embT,
                                                   float* __restrict__ bnorm,
                                                   short* __restrict__ ehi,
                                                   short* __restrict__ elo,
                                                   unsigned int* __restrict__ hist,
                                                   float* __restrict__ misc) {
    const int k = blockIdx.x;     // 0..1023
    const int t = threadIdx.x;    // 0..255 = c
    float v = emb[k*CCH + t];
    embT[(size_t)t*KKE + k] = v;
    // bf16 split (RNE): v = hi + lo + eps(~2^-18 |v|)
    __hip_bfloat16 h = __float2bfloat16(v);
    float hf = __bfloat162float(h);
    __hip_bfloat16 l = __float2bfloat16(v - hf);
    size_t eoff = (size_t)(t >> 5)*32768 + (size_t)k*32 + (t & 31);
    ehi[eoff] = *(short*)&h;
    elo[eoff] = *(short*)&l;
    double sq = (double)v * (double)v;
    #pragma unroll
    for (int off = 32; off; off >>= 1) sq += __shfl_down(sq, off);
    __shared__ double wred[4];
    const int wave = t >> 6, lane = t & 63;
    if (lane == 0) wred[wave] = sq;
    __syncthreads();
    if (t == 0) bnorm[k] = (float)(wred[0] + wred[1] + wred[2] + wred[3]);
    if (blockIdx.x < 4) hist[blockIdx.x*256 + t] = 0u;
    if (blockIdx.x == 4 && t == 0) { misc[0] = 0.0f; ((int*)misc)[1] = 0; }
}

// ---------------- Kernel 1b: ||x_n||^2 fp64
__global__ __launch_bounds__(256) void anorm_kernel(const float* __restrict__ inp,
                                                    float* __restrict__ anorm) {
    const int b  = blockIdx.y;
    const int hw = blockIdx.x * 256 + threadIdx.x;
    const float* p = inp + (size_t)b*CCH*HWN + hw;
    double s = 0.0;
    #pragma unroll 8
    for (int c = 0; c < CCH; ++c) {
        float v = p[(size_t)c*HWN];
        s += (double)v * (double)v;
    }
    anorm[b*HWN + hw] = (float)s;
}

// ---------------- Kernel 2: MFMA distance + per-k-block argmin candidates
// grid (512 n-tiles, 8 k-tiles), 256 thr = 4 waves, block tile 128n x 128k.
// Waves in 2x2: wave tile 64n x 64k = 4 rowgroups x 4 coltiles (16x16x32 bf16).
// Per chunk per wave: 8 A-frag + 8 B-frag ds_read_b128 for 48 MFMAs.
__global__ __launch_bounds__(256, 3) void argmin_mfma(const float* __restrict__ inp,
                                                      const short* __restrict__ ehi,
                                                      const short* __restrict__ elo,
                                                      const float* __restrict__ anorm,
                                                      const float* __restrict__ bnorm,
                                                      float* __restrict__ cd1,
                                                      int* __restrict__ ck1,
                                                      float* __restrict__ cd2) {
    __shared__ short Ahi[128*APAD];
    __shared__ short Alo[128*APAD];
    __shared__ short Bhi[128*APAD];
    __shared__ short Blo[128*APAD];
    __shared__ float m_d1[2][128];
    __shared__ float m_d2[2][128];
    __shared__ int   m_k1[2][128];

    const int t    = threadIdx.x;
    const int w    = t >> 6;
    const int lane = t & 63;
    const int q    = lane >> 4;      // quad 0..3
    const int l15  = lane & 15;
    const int wn   = (w & 1) * 64;   // wave's n-offset in tile
    const int wkh  = w >> 1;         // wave's k-half
    const int wk   = wkh * 64;       // wave's k-offset in tile
    const int n0   = blockIdx.x * 128;
    const int k0   = blockIdx.y * 128;
    const int b    = n0 >> 10;
    const int hw0  = n0 & 1023;
    const float* gA = inp + (size_t)b*CCH*HWN + hw0;

    const int na = t & 127;          // A staging: row
    const int ch = t >> 7;           // A staging: c-half (16 c each)
    const int br = t >> 2;           // B staging: code row 0..63
    const int bc = (t & 3) * 8;      // B staging: c offset

    f32x4 acc[4][4];
    #pragma unroll
    for (int i = 0; i < 4; ++i)
        #pragma unroll
        for (int j = 0; j < 4; ++j) acc[i][j] = (f32x4){0.f,0.f,0.f,0.f};

    for (int chunk = 0; chunk < 8; ++chunk) {
        const int c0 = chunk * 32;
        __syncthreads();
        // ---- A: read 16 fp32 (coalesced over na), split, write 2x b128 each
        float v[16];
        #pragma unroll
        for (int cc = 0; cc < 16; ++cc)
            v[cc] = gA[(size_t)(c0 + ch*16 + cc) * HWN + na];
        short hs[16], ls[16];
        #pragma unroll
        for (int cc = 0; cc < 16; ++cc) {
            __hip_bfloat16 h = __float2bfloat16(v[cc]);
            float hf = __bfloat162float(h);
            __hip_bfloat16 l = __float2bfloat16(v[cc] - hf);
            hs[cc] = *(short*)&h; ls[cc] = *(short*)&l;
        }
        *(s16x8*)&Ahi[na*APAD + ch*16]     = *(s16x8*)&hs[0];
        *(s16x8*)&Ahi[na*APAD + ch*16 + 8] = *(s16x8*)&hs[8];
        *(s16x8*)&Alo[na*APAD + ch*16]     = *(s16x8*)&ls[0];
        *(s16x8*)&Alo[na*APAD + ch*16 + 8] = *(s16x8*)&ls[8];
        // ---- B: copy pre-split chunked tile (coalesced src, padded dst)
        {
            const size_t ebase = (size_t)chunk*32768 + (size_t)k0*32;
            *(s16x8*)&Bhi[br*APAD + bc]      = *(const s16x8*)&ehi[ebase + t*8];
            *(s16x8*)&Bhi[(64+br)*APAD + bc] = *(const s16x8*)&ehi[ebase + 2048 + t*8];
            *(s16x8*)&Blo[br*APAD + bc]      = *(const s16x8*)&elo[ebase + t*8];
            *(s16x8*)&Blo[(64+br)*APAD + bc] = *(const s16x8*)&elo[ebase + 2048 + t*8];
        }
        __syncthreads();
        // ---- frags: 4 A rowgroups (hi+lo), then sweep 4 B coltiles
        s16x8 ah[4], al[4];
        #pragma unroll
        for (int rg = 0; rg < 4; ++rg) {
            ah[rg] = *(s16x8*)&Ahi[(wn + rg*16 + l15)*APAD + q*8];
            al[rg] = *(s16x8*)&Alo[(wn + rg*16 + l15)*APAD + q*8];
        }
        #pragma unroll
        for (int ct = 0; ct < 4; ++ct) {
            s16x8 bh = *(s16x8*)&Bhi[(wk + ct*16 + l15)*APAD + q*8];
            s16x8 bl = *(s16x8*)&Blo[(wk + ct*16 + l15)*APAD + q*8];
            #pragma unroll
            for (int rg = 0; rg < 4; ++rg) {
                acc[rg][ct] = __builtin_amdgcn_mfma_f32_16x16x32_bf16(ah[rg], bh, acc[rg][ct], 0, 0, 0);
                acc[rg][ct] = __builtin_amdgcn_mfma_f32_16x16x32_bf16(ah[rg], bl, acc[rg][ct], 0, 0, 0);
                acc[rg][ct] = __builtin_amdgcn_mfma_f32_16x16x32_bf16(al[rg], bh, acc[rg][ct], 0, 0, 0);
            }
        }
    }

    // ---- epilogue: d = (anorm+bnorm) - 2*dot; per-row best/2nd over this wave's 64 k
    float bnv[4];
    #pragma unroll
    for (int ct = 0; ct < 4; ++ct) bnv[ct] = bnorm[k0 + wk + ct*16 + l15];

    #pragma unroll
    for (int rg = 0; rg < 4; ++rg) {
        #pragma unroll
        for (int reg = 0; reg < 4; ++reg) {
            const int nl = wn + rg*16 + q*4 + reg;         // C/D: row = quad*4+reg
            const float a = anorm[n0 + nl];
            float d1 = FLT_MAX, d2 = FLT_MAX; int k1 = 0;
            #pragma unroll
            for (int ct = 0; ct < 4; ++ct) {
                float s = a + bnv[ct];
                float d = s - 2.0f * acc[rg][ct][reg];
                int   k = k0 + wk + ct*16 + l15;           // C/D: col = lane&15
                if (d < d1 || (d == d1 && k < k1)) { d2 = d1; d1 = d; k1 = k; }
                else d2 = fminf(d2, d);
            }
            #pragma unroll
            for (int off = 1; off < 16; off <<= 1) {
                float od1 = __shfl_xor(d1, off);
                int   ok1 = __shfl_xor(k1, off);
                float od2 = __shfl_xor(d2, off);
                merge_cand(d1, k1, d2, od1, ok1, od2);
            }
            if (l15 == 0) {                                // one lane per (row, k-half)
                m_d1[wkh][nl] = d1; m_k1[wkh][nl] = k1; m_d2[wkh][nl] = d2;
            }
        }
    }
    __syncthreads();
    if (t < 128) {
        float d1 = m_d1[0][t]; int k1 = m_k1[0][t]; float d2 = m_d2[0][t];
        merge_cand(d1, k1, d2, m_d1[1][t], m_k1[1][t], m_d2[1][t]);
        const size_t o = (size_t)blockIdx.y*NTOT + n0 + t;
        cd1[o] = d1; ck1[o] = k1; cd2[o] = d2;
    }
}

// ---------------- Kernel 3: merge 8 k-block candidates, flag near-ties
__global__ __launch_bounds__(256) void reduce_kernel(const float* __restrict__ cd1,
                                                     const int* __restrict__ ck1,
                                                     const float* __restrict__ cd2,
                                                     int* __restrict__ idx,
                                                     int* __restrict__ list,
                                                     int* __restrict__ counter) {
    const int n = blockIdx.x*256 + threadIdx.x;
    float d1 = cd1[n]; int k1 = ck1[n]; float d2 = cd2[n];
    #pragma unroll
    for (int kb = 1; kb < 8; ++kb) {
        const size_t o = (size_t)kb*NTOT + n;
        merge_cand(d1, k1, d2, cd1[o], ck1[o], cd2[o]);
    }
    idx[n] = k1;
    if (d2 - d1 < TAU) {
        int p = atomicAdd(counter, 1);
        list[p] = n;
    }
}

// ---------------- Kernel 4: exact fp32 rescore (reference sequential-c semantics),
// coalesced via embT: at fixed c, thread t reads embT[c*1024 + kk*256 + t].
__global__ __launch_bounds__(256) void rescore_kernel(const float* __restrict__ inp,
                                                      const float* __restrict__ embT,
                                                      const float* __restrict__ anorm,
                                                      const float* __restrict__ bnorm,
                                                      const int* __restrict__ list,
                                                      const int* __restrict__ counter,
                                                      int* __restrict__ idx) {
    __shared__ float xs[256];
    __shared__ float rd[256];
    __shared__ int   rk[256];
    const int t = threadIdx.x;
    const int cnt = *counter;
    for (int f = blockIdx.x; f < cnt; f += gridDim.x) {
        const int n = list[f];
        const int b = n >> 10, hw = n & 1023;
        __syncthreads();
        xs[t] = inp[(size_t)b*CCH*HWN + (size_t)t*HWN + hw];
        __syncthreads();
        float dot0 = 0.f, dot1 = 0.f, dot2 = 0.f, dot3 = 0.f;
        #pragma unroll 4
        for (int c = 0; c < CCH; ++c) {
            const float xc = xs[c];
            const float* row = embT + (size_t)c*KKE + t;
            dot0 += xc * row[0];
            dot1 += xc * row[256];
            dot2 += xc * row[512];
            dot3 += xc * row[768];
        }
        const float a = anorm[n];
        float bd = FLT_MAX; int bk = 0;
        float dots[4] = {dot0, dot1, dot2, dot3};
        #pragma unroll
        for (int kk = 0; kk < 4; ++kk) {
            const int k = kk*256 + t;
            float s = a + bnorm[k];
            float d = s - 2.0f * dots[kk];
            if (d < bd || (d == bd && k < bk)) { bd = d; bk = k; }
        }
        rd[t] = bd; rk[t] = bk;
        __syncthreads();
        for (int stride = 128; stride; stride >>= 1) {
            if (t < stride) {
                float od = rd[t+stride]; int ok = rk[t+stride];
                if (od < rd[t] || (od == rd[t] && ok < rk[t])) { rd[t] = od; rk[t] = ok; }
            }
            __syncthreads();
        }
        if (t == 0) idx[n] = rk[0];
    }
}

// ---------------- Kernel 5: encodings one-hot + histogram (16 rows/block)
__global__ __launch_bounds__(256) void onehot_kernel(const int* __restrict__ idx,
                                                     float* __restrict__ enc,
                                                     unsigned int* __restrict__ hist) {
    const int t = threadIdx.x;
    const int j4 = t * 4;
    for (int r = 0; r < 16; ++r) {
        const int n = blockIdx.x*16 + r;
        const int k = idx[n];
        float2 v0 = {0.0f, 0.0f}, v1 = {0.0f, 0.0f};
        if (k == j4)     v0.x = 1.0f;
        if (k == j4 + 1) v0.y = 1.0f;
        if (k == j4 + 2) v1.x = 1.0f;
        if (k == j4 + 3) v1.y = 1.0f;
        float* row = enc + (size_t)n * KKE;
        *(float2*)&row[j4]     = v0;
        *(float2*)&row[j4 + 2] = v1;
        if (t == 0) atomicAdd(&hist[k], 1u);
    }
}

// ---------------- Kernel 6: out = gather(e), loss partials
__global__ __launch_bounds__(256) void out_loss_kernel(const float* __restrict__ inp,
                                                       const float* __restrict__ embT,
                                                       const int* __restrict__ idx,
                                                       float* __restrict__ out,
                                                       float* __restrict__ lossacc) {
    const int t = threadIdx.x;
    const size_t stride = (size_t)gridDim.x * 256;
    float lsum = 0.0f;
    for (size_t m = (size_t)blockIdx.x * 256 + t; m < (size_t)OUT_ELE; m += stride) {
        int hw = (int)(m & 1023);
        int c  = (int)((m >> 10) & 255);
        int b  = (int)(m >> 18);
        int k  = idx[b*HWN + hw];
        float e = embT[(size_t)c*KKE + k];
        float x = inp[m];
        out[m] = e;
        float df = e - x;
        lsum += df * df;
    }
    #pragma unroll
    for (int off = 32; off; off >>= 1) lsum += __shfl_down(lsum, off);
    __shared__ float wred[4];
    const int wave = t >> 6, lane = t & 63;
    if (lane == 0) wred[wave] = lsum;
    __syncthreads();
    if (t == 0) atomicAdd(lossacc, wred[0] + wred[1] + wred[2] + wred[3]);
}

// ---------------- Kernel 7: finalize
__global__ __launch_bounds__(1024) void final_kernel(const unsigned int* __restrict__ hist,
                                                     const float* __restrict__ lossacc,
                                                     float* __restrict__ d_out) {
    const int t = threadIdx.x;
    float p = (float)hist[t] * (1.0f / 65536.0f);
    float v = p * logf(p + 1e-10f);
    #pragma unroll
    for (int off = 32; off; off >>= 1) v += __shfl_down(v, off);
    __shared__ float wred[16];
    const int wave = t >> 6, lane = t & 63;
    if (lane == 0) wred[wave] = v;
    __syncthreads();
    if (t == 0) {
        float s = 0.0f;
        #pragma unroll
        for (int i = 0; i < 16; ++i) s += wred[i];
        d_out[PERP_OFF] = expf(-s);
        d_out[LOSS_OFF] = 1.25f * (*lossacc) * (1.0f / (float)OUT_ELE);
    }
}

extern "C" void kernel_launch(void* const* d_in, const int* in_sizes, int n_in,
                              void* d_out, int out_size, void* d_ws, size_t ws_size,
                              hipStream_t stream) {
    (void)in_sizes; (void)n_in; (void)out_size; (void)ws_size;
    const float* inp = (const float*)d_in[0];
    const float* emb = (const float*)d_in[1];
    float* out = (float*)d_out;
    char* ws = (char*)d_ws;
    int*          idx     = (int*)(ws + WS_IDX);
    float*        anorm   = (float*)(ws + WS_ANORM);
    unsigned int* hist    = (unsigned int*)(ws + WS_HIST);
    float*        bnorm   = (float*)(ws + WS_BNORM);
    float*        misc    = (float*)(ws + WS_MISC);
    int*          list    = (int*)(ws + WS_LIST);
    float*        embT    = (float*)(ws + WS_EMBT);
    short*        ehi     = (short*)(ws + WS_EHI);
    short*        elo     = (short*)(ws + WS_ELO);
    float*        cd1     = (float*)(ws + WS_CD1);
    int*          ck1     = (int*)(ws + WS_CK1);
    float*        cd2     = (float*)(ws + WS_CD2);
    int*          counter = ((int*)misc) + 1;

    prep_kernel<<<dim3(KKE), dim3(256), 0, stream>>>(emb, embT, bnorm, ehi, elo, hist, misc);
    anorm_kernel<<<dim3(4, BB), dim3(256), 0, stream>>>(inp, anorm);
    argmin_mfma<<<dim3(512, 8), dim3(256), 0, stream>>>(inp, ehi, elo, anorm, bnorm, cd1, ck1, cd2);
    reduce_kernel<<<dim3(256), dim3(256), 0, stream>>>(cd1, ck1, cd2, idx, list, counter);
    rescore_kernel<<<dim3(512), dim3(256), 0, stream>>>(inp, embT, anorm, bnorm, list, counter, idx);
    onehot_kernel<<<dim3(4096), dim3(256), 0, stream>>>(idx, out + ENC_OFF, hist);
    out_loss_kernel<<<dim3(4096), dim3(256), 0, stream>>>(inp, embT, idx, out + OUT_OFF, misc);
    final_kernel<<<dim3(1), dim3(1024), 0, stream>>>(hist, misc, out);
}